// Round 1
// baseline (293.416 us; speedup 1.0000x reference)
//
#include <hip/hip_runtime.h>
#include <math.h>

#define EPSV 1e-5f

// ---------------------------------------------------------------------------
// Kernel 1: fused ReLU + strip pooling.
// x is [B=64][C=1024][H=44][W=16] fp32. Each pooling strip (4 h-rows x 16 w)
// is exactly 64 CONTIGUOUS floats; the whole tensor partitions into
// 64*1024*11 = 720896 consecutive 64-float chunks.
// chunk id g = (b*1024 + c)*11 + s, memory offset g*64.
// 16 lanes cooperate per chunk: each lane loads one float4 (fully coalesced,
// 16B/lane), relu+sum, then shfl_xor reduce within the 16-lane group.
// ---------------------------------------------------------------------------
__global__ __launch_bounds__(256) void pool_relu_kernel(
    const float* __restrict__ x, float* __restrict__ P)
{
    int t = blockIdx.x * blockDim.x + threadIdx.x;      // one float4 per thread
    const float4 v = reinterpret_cast<const float4*>(x)[t];
    float s = fmaxf(v.x, 0.f) + fmaxf(v.y, 0.f) + fmaxf(v.z, 0.f) + fmaxf(v.w, 0.f);
    s += __shfl_xor(s, 1);
    s += __shfl_xor(s, 2);
    s += __shfl_xor(s, 4);
    s += __shfl_xor(s, 8);
    if ((threadIdx.x & 15) == 0) P[t >> 4] = s * (1.0f / 64.0f);
}

// ---------------------------------------------------------------------------
// Kernel 2: everything else, one block (256 threads) per batch image.
// P[b] is [c=1024][s=11]. Steps:
//  y[d,s]   = BN1(sum_c dr_w[d,c] * P[b,c,s] + dr_b[d])      (22x11)
//  z[s,d]   = y[d,s]                                          (11 strips, 22 samples)
//  A        = centered covariance (11x11), tr = trace
//  Newton-Schulz iterN=5 -> S = 0.5*(Y@(3I - Z@Y))*sqrt(tr)
//  row BN -> grouped conv (11 groups x 4) -> fc 44->11 -> sigmoid
//  broadcast a[strip] to out[b,1,44,16]
// ---------------------------------------------------------------------------
__global__ __launch_bounds__(256) void somm_tail_kernel(
    const float* __restrict__ P,
    const float* __restrict__ dr_w, const float* __restrict__ dr_b,
    const float* __restrict__ bn1_g, const float* __restrict__ bn1_b,
    const float* __restrict__ bn1_m, const float* __restrict__ bn1_v,
    const float* __restrict__ rbn_g, const float* __restrict__ rbn_b,
    const float* __restrict__ rbn_m, const float* __restrict__ rbn_v,
    const float* __restrict__ rcw, const float* __restrict__ rcb,
    const float* __restrict__ fcw, const float* __restrict__ fcb,
    float* __restrict__ out)
{
    const int b   = blockIdx.x;
    const int tid = threadIdx.x;

    // Pl[s][c], padded stride 1028 floats (16B aligned, bank step 4 -> only
    // free 2-way conflicts among 11 strips). 45232 B.
    __shared__ float Pl[11][1028];
    __shared__ float z[11][22];
    __shared__ float An[128], Tm[128], Ym[128], Zm[128], M1[128], Y2[128], Z2[128];
    __shared__ float zmean[11], trsh;
    __shared__ float gsh[44], ash[11];

    const float* Pb = P + b * (1024 * 11);
    for (int idx = tid; idx < 1024 * 11; idx += 256) {
        int c = idx / 11;
        int s = idx - c * 11;
        Pl[s][c] = Pb[idx];
    }
    __syncthreads();

    // 22x11 outputs, dot over 1024 (float4-vectorized)
    if (tid < 242) {
        int d = tid / 11, s = tid - d * 11;
        const float4* wrow = reinterpret_cast<const float4*>(dr_w + d * 1024);
        const float4* prow = reinterpret_cast<const float4*>(&Pl[s][0]);
        float acc = 0.f;
#pragma unroll 8
        for (int c4 = 0; c4 < 256; ++c4) {
            float4 w = wrow[c4];
            float4 p = prow[c4];
            acc += w.x * p.x + w.y * p.y + w.z * p.z + w.w * p.w;
        }
        float s1 = bn1_g[d] / sqrtf(bn1_v[d] + EPSV);
        z[s][d] = (acc + dr_b[d] - bn1_m[d]) * s1 + bn1_b[d];
    }
    __syncthreads();

    if (tid < 11) {
        float m = 0.f;
        for (int d2 = 0; d2 < 22; ++d2) m += z[tid][d2];
        zmean[tid] = m * (1.f / 22.f);
    }
    __syncthreads();

    const int i = tid / 11, j = tid - (tid / 11) * 11;  // valid when tid<121

    // A = zc @ zc^T / 22
    if (tid < 121) {
        float mi = zmean[i], mj = zmean[j];
        float acc = 0.f;
        for (int d2 = 0; d2 < 22; ++d2)
            acc += (z[i][d2] - mi) * (z[j][d2] - mj);
        An[tid] = acc * (1.f / 22.f);
    }
    __syncthreads();
    if (tid == 0) {
        float tr = 0.f;
        for (int k = 0; k < 11; ++k) tr += An[k * 11 + k];
        trsh = tr;
    }
    __syncthreads();
    const float tr = trsh;

    // An = A/tr ; T = 0.5*(3I - An) ; Y = An@T ; Z = T
    if (tid < 121) {
        float an = An[tid] / tr;
        An[tid] = an;
        Tm[tid] = (i == j ? 1.5f : 0.f) - 0.5f * an;
    }
    __syncthreads();
    if (tid < 121) {
        float acc = 0.f;
        for (int k = 0; k < 11; ++k) acc += An[i * 11 + k] * Tm[k * 11 + j];
        Ym[tid] = acc;
        Zm[tid] = Tm[tid];
    }
    __syncthreads();

    for (int it = 0; it < 3; ++it) {
        if (tid < 121) {
            float acc = 0.f;
            for (int k = 0; k < 11; ++k) acc += Zm[i * 11 + k] * Ym[k * 11 + j];
            M1[tid] = acc;
        }
        __syncthreads();
        if (tid < 121) Tm[tid] = (i == j ? 1.5f : 0.f) - 0.5f * M1[tid];
        __syncthreads();
        if (tid < 121) {
            float accY = 0.f, accZ = 0.f;
            for (int k = 0; k < 11; ++k) {
                accY += Ym[i * 11 + k] * Tm[k * 11 + j];
                accZ += Tm[i * 11 + k] * Zm[k * 11 + j];
            }
            Y2[tid] = accY;
            Z2[tid] = accZ;
        }
        __syncthreads();
        if (tid < 121) { Ym[tid] = Y2[tid]; Zm[tid] = Z2[tid]; }
        __syncthreads();
    }

    // S = 0.5*(Y @ (3I - Z@Y))*sqrt(tr), then row-wise BN -> v (in Y2)
    if (tid < 121) {
        float acc = 0.f;
        for (int k = 0; k < 11; ++k) acc += Zm[i * 11 + k] * Ym[k * 11 + j];
        M1[tid] = (i == j ? 3.f : 0.f) - acc;
    }
    __syncthreads();
    if (tid < 121) {
        float acc = 0.f;
        for (int k = 0; k < 11; ++k) acc += Ym[i * 11 + k] * M1[k * 11 + j];
        float S  = 0.5f * acc * sqrtf(tr);
        float rs = rbn_g[i] / sqrtf(rbn_v[i] + EPSV);
        Y2[tid]  = (S - rbn_m[i]) * rs + rbn_b[i];
    }
    __syncthreads();

    // grouped conv: g[c,j] = relu(sum_h v[c,h]*rcw[c,j,h] + rcb[c,j])
    if (tid < 44) {
        int c = tid >> 2;
        float acc = rcb[tid];
        for (int h = 0; h < 11; ++h) acc += Y2[c * 11 + h] * rcw[tid * 11 + h];
        gsh[tid] = fmaxf(acc, 0.f);
    }
    __syncthreads();

    // fc 44 -> 11, sigmoid
    if (tid < 11) {
        float acc = fcb[tid];
        for (int k = 0; k < 44; ++k) acc += gsh[k] * fcw[tid * 44 + k];
        ash[tid] = 1.f / (1.f + expf(-acc));
    }
    __syncthreads();

    // out[b,1,h,w] = a[h/4]; idx = h*16+w -> strip = idx/64
    for (int idx = tid; idx < 704; idx += 256) {
        out[b * 704 + idx] = ash[idx >> 6];
    }
}

extern "C" void kernel_launch(void* const* d_in, const int* in_sizes, int n_in,
                              void* d_out, int out_size, void* d_ws, size_t ws_size,
                              hipStream_t stream) {
    const float* x     = (const float*)d_in[0];
    const float* dr_w  = (const float*)d_in[1];
    const float* dr_b  = (const float*)d_in[2];
    const float* bn1_g = (const float*)d_in[3];
    const float* bn1_b = (const float*)d_in[4];
    const float* bn1_m = (const float*)d_in[5];
    const float* bn1_v = (const float*)d_in[6];
    const float* rbn_g = (const float*)d_in[7];
    const float* rbn_b = (const float*)d_in[8];
    const float* rbn_m = (const float*)d_in[9];
    const float* rbn_v = (const float*)d_in[10];
    const float* rcw   = (const float*)d_in[11];
    const float* rcb   = (const float*)d_in[12];
    const float* fcw   = (const float*)d_in[13];
    const float* fcb   = (const float*)d_in[14];
    float* out = (float*)d_out;
    float* P   = (float*)d_ws;  // 64*1024*11 floats = 2.88 MB

    // 46137344 floats / 4 per thread / 256 per block = 45056 blocks (exact)
    pool_relu_kernel<<<45056, 256, 0, stream>>>(x, P);
    somm_tail_kernel<<<64, 256, 0, stream>>>(P, dr_w, dr_b, bn1_g, bn1_b, bn1_m,
                                             bn1_v, rbn_g, rbn_b, rbn_m, rbn_v,
                                             rcw, rcb, fcw, fcb, out);
}

// Round 2
// 291.963 us; speedup vs baseline: 1.0050x; 1.0050x over previous
//
#include <hip/hip_runtime.h>
#include <math.h>

#define EPSV 1e-5f

// ---------------------------------------------------------------------------
// Kernel A: fused ReLU + strip-pool + partial 1x1-conv reduction.
// x is [B=64][C=1024][H=44][W=16] fp32; each pooling strip = 64 contiguous
// floats. Block = (batch b, channel-group cg of 32 channels):
//   phase 1: pool 32x11 strip means into LDS (fully coalesced float4 reads,
//            16-lane shfl reduce per 64-float chunk)
//   phase 2: partial z[d,s] = sum_{cl<32} dr_w[d,c0+cl] * P[cl,s]  (242 vals)
// Partials are written to separate slots (deterministic, no atomics).
// ---------------------------------------------------------------------------
__global__ __launch_bounds__(256) void fused_pool_mm_kernel(
    const float* __restrict__ x, const float* __restrict__ dr_w,
    float* __restrict__ zpart)
{
    __shared__ float Pl[352];                 // [cl=32][s=11]
    const int t  = threadIdx.x;
    const int b  = blockIdx.x >> 5;
    const int cg = blockIdx.x & 31;
    const int c0 = cg * 32;

    const float4* x4 = reinterpret_cast<const float4*>(x)
                     + (size_t)(b * 1024 + c0) * 176;   // 176 float4 per channel
#pragma unroll
    for (int k = 0; k < 22; ++k) {
        float4 v = x4[k * 256 + t];
        float s = fmaxf(v.x, 0.f) + fmaxf(v.y, 0.f)
                + fmaxf(v.z, 0.f) + fmaxf(v.w, 0.f);
        s += __shfl_xor(s, 1);
        s += __shfl_xor(s, 2);
        s += __shfl_xor(s, 4);
        s += __shfl_xor(s, 8);
        if ((t & 15) == 0) Pl[k * 16 + (t >> 4)] = s * (1.f / 64.f);
    }
    __syncthreads();

    if (t < 242) {
        const int d = t / 11, sIdx = t - d * 11;
        const float4* wr = reinterpret_cast<const float4*>(dr_w + d * 1024 + c0);
        float acc = 0.f;
#pragma unroll
        for (int q = 0; q < 8; ++q) {
            float4 w = wr[q];
            acc += w.x * Pl[(4 * q + 0) * 11 + sIdx]
                 + w.y * Pl[(4 * q + 1) * 11 + sIdx]
                 + w.z * Pl[(4 * q + 2) * 11 + sIdx]
                 + w.w * Pl[(4 * q + 3) * 11 + sIdx];
        }
        zpart[blockIdx.x * 242 + t] = acc;
    }
}

// ---------------------------------------------------------------------------
// Kernel B: tiny tail, one block per batch image.
//  z[s,d] = BN1(sum_cg zpart + dr_b)          (11 strips, 22 samples)
//  A = centered covariance (11x11); Newton-Schulz iterN=5 -> sqrtm S
//  row BN -> grouped conv (11 groups x 4) -> fc 44->11 -> sigmoid
//  broadcast a[strip] to out[b,1,44,16]
// ---------------------------------------------------------------------------
__global__ __launch_bounds__(256) void somm_tail_kernel(
    const float* __restrict__ zpart,
    const float* __restrict__ dr_b,
    const float* __restrict__ bn1_g, const float* __restrict__ bn1_b,
    const float* __restrict__ bn1_m, const float* __restrict__ bn1_v,
    const float* __restrict__ rbn_g, const float* __restrict__ rbn_b,
    const float* __restrict__ rbn_m, const float* __restrict__ rbn_v,
    const float* __restrict__ rcw, const float* __restrict__ rcb,
    const float* __restrict__ fcw, const float* __restrict__ fcb,
    float* __restrict__ out)
{
    const int b   = blockIdx.x;
    const int tid = threadIdx.x;

    __shared__ float z[11][22];
    __shared__ float An[128], Tm[128], Ym[128], Zm[128], M1[128], Y2[128], Z2[128];
    __shared__ float zmean[11], trsh;
    __shared__ float gsh[44], ash[11];

    // sum the 32 channel-group partials, fold BN1 affine
    if (tid < 242) {
        const int d = tid / 11, sIdx = tid - d * 11;
        float acc = 0.f;
#pragma unroll
        for (int cg = 0; cg < 32; ++cg)
            acc += zpart[(b * 32 + cg) * 242 + tid];
        float s1 = bn1_g[d] / sqrtf(bn1_v[d] + EPSV);
        z[sIdx][d] = (acc + dr_b[d] - bn1_m[d]) * s1 + bn1_b[d];
    }
    __syncthreads();

    if (tid < 11) {
        float m = 0.f;
        for (int d2 = 0; d2 < 22; ++d2) m += z[tid][d2];
        zmean[tid] = m * (1.f / 22.f);
    }
    __syncthreads();

    const int i = tid / 11, j = tid - (tid / 11) * 11;  // valid when tid<121

    // A = zc @ zc^T / 22
    if (tid < 121) {
        float mi = zmean[i], mj = zmean[j];
        float acc = 0.f;
        for (int d2 = 0; d2 < 22; ++d2)
            acc += (z[i][d2] - mi) * (z[j][d2] - mj);
        An[tid] = acc * (1.f / 22.f);
    }
    __syncthreads();
    if (tid == 0) {
        float tr = 0.f;
        for (int k = 0; k < 11; ++k) tr += An[k * 11 + k];
        trsh = tr;
    }
    __syncthreads();
    const float tr = trsh;

    // An = A/tr ; T = 0.5*(3I - An) ; Y = An@T ; Z = T
    if (tid < 121) {
        float an = An[tid] / tr;
        An[tid] = an;
        Tm[tid] = (i == j ? 1.5f : 0.f) - 0.5f * an;
    }
    __syncthreads();
    if (tid < 121) {
        float acc = 0.f;
        for (int k = 0; k < 11; ++k) acc += An[i * 11 + k] * Tm[k * 11 + j];
        Ym[tid] = acc;
        Zm[tid] = Tm[tid];
    }
    __syncthreads();

    for (int it = 0; it < 3; ++it) {
        if (tid < 121) {
            float acc = 0.f;
            for (int k = 0; k < 11; ++k) acc += Zm[i * 11 + k] * Ym[k * 11 + j];
            M1[tid] = acc;
        }
        __syncthreads();
        if (tid < 121) Tm[tid] = (i == j ? 1.5f : 0.f) - 0.5f * M1[tid];
        __syncthreads();
        if (tid < 121) {
            float accY = 0.f, accZ = 0.f;
            for (int k = 0; k < 11; ++k) {
                accY += Ym[i * 11 + k] * Tm[k * 11 + j];
                accZ += Tm[i * 11 + k] * Zm[k * 11 + j];
            }
            Y2[tid] = accY;
            Z2[tid] = accZ;
        }
        __syncthreads();
        if (tid < 121) { Ym[tid] = Y2[tid]; Zm[tid] = Z2[tid]; }
        __syncthreads();
    }

    // S = 0.5*(Y @ (3I - Z@Y))*sqrt(tr), then row-wise BN -> v (in Y2)
    if (tid < 121) {
        float acc = 0.f;
        for (int k = 0; k < 11; ++k) acc += Zm[i * 11 + k] * Ym[k * 11 + j];
        M1[tid] = (i == j ? 3.f : 0.f) - acc;
    }
    __syncthreads();
    if (tid < 121) {
        float acc = 0.f;
        for (int k = 0; k < 11; ++k) acc += Ym[i * 11 + k] * M1[k * 11 + j];
        float S  = 0.5f * acc * sqrtf(tr);
        float rs = rbn_g[i] / sqrtf(rbn_v[i] + EPSV);
        Y2[tid]  = (S - rbn_m[i]) * rs + rbn_b[i];
    }
    __syncthreads();

    // grouped conv: g[c,j] = relu(sum_h v[c,h]*rcw[c,j,h] + rcb[c,j])
    if (tid < 44) {
        int c = tid >> 2;
        float acc = rcb[tid];
        for (int h = 0; h < 11; ++h) acc += Y2[c * 11 + h] * rcw[tid * 11 + h];
        gsh[tid] = fmaxf(acc, 0.f);
    }
    __syncthreads();

    // fc 44 -> 11, sigmoid
    if (tid < 11) {
        float acc = fcb[tid];
        for (int k = 0; k < 44; ++k) acc += gsh[k] * fcw[tid * 44 + k];
        ash[tid] = 1.f / (1.f + expf(-acc));
    }
    __syncthreads();

    // out[b,1,h,w] = a[h/4]; idx = h*16+w -> strip = idx/64
    for (int idx = tid; idx < 704; idx += 256) {
        out[b * 704 + idx] = ash[idx >> 6];
    }
}

extern "C" void kernel_launch(void* const* d_in, const int* in_sizes, int n_in,
                              void* d_out, int out_size, void* d_ws, size_t ws_size,
                              hipStream_t stream) {
    const float* x     = (const float*)d_in[0];
    const float* dr_w  = (const float*)d_in[1];
    const float* dr_b  = (const float*)d_in[2];
    const float* bn1_g = (const float*)d_in[3];
    const float* bn1_b = (const float*)d_in[4];
    const float* bn1_m = (const float*)d_in[5];
    const float* bn1_v = (const float*)d_in[6];
    const float* rbn_g = (const float*)d_in[7];
    const float* rbn_b = (const float*)d_in[8];
    const float* rbn_m = (const float*)d_in[9];
    const float* rbn_v = (const float*)d_in[10];
    const float* rcw   = (const float*)d_in[11];
    const float* rcb   = (const float*)d_in[12];
    const float* fcw   = (const float*)d_in[13];
    const float* fcb   = (const float*)d_in[14];
    float* out   = (float*)d_out;
    float* zpart = (float*)d_ws;   // 64*32*242 floats = 1.98 MB

    fused_pool_mm_kernel<<<64 * 32, 256, 0, stream>>>(x, dr_w, zpart);
    somm_tail_kernel<<<64, 256, 0, stream>>>(zpart, dr_b, bn1_g, bn1_b, bn1_m,
                                             bn1_v, rbn_g, rbn_b, rbn_m, rbn_v,
                                             rcw, rcb, fcw, fcb, out);
}